// Round 10
// baseline (1461.300 us; speedup 1.0000x reference)
//
#include <hip/hip_runtime.h>
#include <hip/hip_bf16.h>

// ---------------------------------------------------------------------------
// TTT meta-adapter fused step, round 10.
// rows = B*S = 4096, H = 1024, R = 16, V = 32000, N_valid = 4094.
// k_fused: R9 structure (RB=32, packed-B, lA staged once, lP double-buffered,
// one barrier per tile, m=0) + INSTRUCTION-LEVEL PHASE FUSION: phase-3 of
// tile t-1 interleaved with phase-1 of tile t in one inner loop so VMEM /
// LDS / MFMA / VALU pipes run concurrently instead of sequentially.
// ---------------------------------------------------------------------------

#define ROWS 4096
#define Hdim 1024
#define Rdim 16
#define Vdim 32000
#define NVALID 4094.0f
#define LRATE 0.01f
#define RB 32          // rows per block in fused kernel
#define VT 512         // V-tile

typedef __attribute__((ext_vector_type(8))) short bf16x8;
typedef __attribute__((ext_vector_type(4))) float f32x4;

static __device__ __forceinline__ float bf2f(short u) {
  union { float f; unsigned int i; } w; w.i = ((unsigned int)(unsigned short)u) << 16; return w.f;
}
static __device__ __forceinline__ short f2bf(float f) {
  union { float f; unsigned int i; } w; w.f = f;
  unsigned int lsb = (w.i >> 16) & 1u;
  w.i += 0x7fffu + lsb;                 // round-to-nearest-even
  return (short)(w.i >> 16);
}
static __device__ __forceinline__ f32x4 mfma16(bf16x8 a, bf16x8 b, f32x4 c) {
  return __builtin_amdgcn_mfma_f32_16x16x32_bf16(a, b, c, 0, 0, 0);
}

// ---------------- workspace layout (bytes) ----------------
#define OFF_BP2   ((size_t)0)                    // lm_head packed [64][1000][512] bf16  65,536,000
#define OFF_BP1   ((size_t)65536000)             // lmhT packed [2000][32][512] bf16     65,536,000
#define OFF_ADP   ((size_t)131072000)            // adapted bf16 [ROWS][H]       8,388,608
#define OFF_DA    ((size_t)139460608)            // bf16 [ROWS][2][H]; f32 [ROWS][H] overlay  16,777,216
#define OFF_U     ((size_t)156237824)            // u f32                          262,144
#define OFF_DU    ((size_t)156499968)            // du f32                         262,144
#define OFF_U2    ((size_t)156762112)            // u2 f32                         262,144
#define OFF_Z     ((size_t)157024256)            // zpart f32 [2][ROWS]             32,768
#define OFF_GA    ((size_t)157089792)            // ga f32                          65,536
#define OFF_GB    ((size_t)157155328)            // gb f32                          65,536
#define OFF_LOSS  ((size_t)157220864)            // loss accumulator                     4

// ---------------- output layout (floats) ----------------
#define OUT_A    ((size_t)4194304)
#define OUT_B    ((size_t)4210688)
#define OUT_LOSS ((size_t)4227072)
#define OUT_GN   ((size_t)4227073)

// ===================== pack lm_head into fragment order =====================
// Bp1[vb][kb][lane][8]: element (v,k)=lm_head[k][v], lane=(v&15)+16*((k>>3)&3), j=k&7
// Bp2[hb][vkb][lane][8]: element (h,v)=lm_head[h][v], lane=(h&15)+16*((v>>3)&3), j=v&7
__global__ void k_pack(const float* __restrict__ in, short* __restrict__ Bp1,
                       short* __restrict__ Bp2) {
  __shared__ short tile[32][258];
  int v0 = blockIdx.x * 256, k0 = blockIdx.y * 32;
  int tid = threadIdx.x;
#pragma unroll
  for (int r = 0; r < 32; ++r)
    tile[r][tid] = f2bf(in[(size_t)(k0 + r) * Vdim + v0 + tid]);
  __syncthreads();
  int lane = tid & 63, l15 = lane & 15, q = (lane >> 4) & 3, g = tid >> 6;
#pragma unroll
  for (int it = 0; it < 4; ++it) {
    int vbl = it * 4 + g;                 // 0..15
    bf16x8 frag;
#pragma unroll
    for (int j = 0; j < 8; ++j) frag[j] = tile[q * 8 + j][vbl * 16 + l15];
    *(bf16x8*)(Bp1 + ((size_t)(v0 / 16 + vbl) * 32 + k0 / 32) * 512 + lane * 8) = frag;
  }
#pragma unroll
  for (int it = 0; it < 4; ++it) {
    int idx = it * 4 + g;                 // 0..15: hbl=idx>>3 (0..1), vkbl=idx&7
    int hbl = idx >> 3, vkbl = idx & 7;
    bf16x8 frag;
#pragma unroll
    for (int j = 0; j < 8; ++j) frag[j] = tile[hbl * 16 + l15][vkbl * 32 + q * 8 + j];
    *(bf16x8*)(Bp2 + ((size_t)(k0 / 16 + hbl) * 1000 + v0 / 32 + vkbl) * 512 + lane * 8) = frag;
  }
}

// ===================== small fp32 kernels =====================

// u = hs @ a : one wave per row
__global__ void k_u(const float* __restrict__ hs, const float* __restrict__ fa,
                    float* __restrict__ u) {
  int w = threadIdx.x >> 6, lane = threadIdx.x & 63;
  int row = blockIdx.x * 4 + w;
  float acc[16];
#pragma unroll
  for (int r = 0; r < 16; ++r) acc[r] = 0.f;
  const float* hrow = hs + (size_t)row * Hdim;
  for (int h = lane; h < Hdim; h += 64) {
    float hv = hrow[h];
    const float* ar = fa + h * Rdim;
#pragma unroll
    for (int r = 0; r < 16; ++r) acc[r] += hv * ar[r];
  }
#pragma unroll
  for (int r = 0; r < 16; ++r)
    for (int off = 32; off; off >>= 1) acc[r] += __shfl_xor(acc[r], off);
  if (lane == 0) {
#pragma unroll
    for (int r = 0; r < 16; ++r) u[row * Rdim + r] = acc[r];
  }
}

// adapted = bf16(hs + u @ b)
__global__ void k_adapted(const float* __restrict__ hs, const float* __restrict__ u,
                          const float* __restrict__ fb, short* __restrict__ adp) {
  size_t gid = (size_t)blockIdx.x * 256 + threadIdx.x;
  int row = (int)(gid >> 10), h = (int)(gid & 1023);
  const float* ur = u + row * Rdim;
  float v = hs[gid];
#pragma unroll
  for (int r = 0; r < 16; ++r) v += ur[r] * fb[r * Hdim + h];
  adp[gid] = f2bf(v);
}

// ===================== fused logits + exp + dA partials =====================
// grid 256 (XCD-swizzled -> 128 rowgroups x 2 V-splits), 1024 threads (16 waves).
__launch_bounds__(1024, 4)
__global__ void k_fused(const short* __restrict__ adp, const short* __restrict__ Bp1,
                        const short* __restrict__ Bp2, short* __restrict__ dApart,
                        float* __restrict__ zpart) {
  __shared__ __align__(16) short lA[RB * 1024];   // adapted rows, full K (swizzled)  64 KB
  __shared__ __align__(16) short lP[2][RB * VT];  // P tile bf16, double-buffered   2x32 KB
  __shared__ float zred[RB * 16];                 //                                   2 KB
  int tid = threadIdx.x, lane = tid & 63, w = tid >> 6;      // w in [0,16)
  int q = lane >> 4, l15 = lane & 15;
  // XCD swizzle: XCDs 0-3 get split 0, XCDs 4-7 get split 1
  int L = blockIdx.x;
  int sp = (L >> 2) & 1;
  int rg = (L & 3) | ((L >> 3) << 2);
  int row0 = rg * RB;
  int v0beg = sp ? 15872 : 0;
  int v0end = sp ? 32000 : 15872;
  int nt = sp ? 32 : 31;

  // stage adapted rows once (read-only afterwards)
#pragma unroll
  for (int i = 0; i < 4; ++i) {
    int idx = tid + i * 1024;
    int r = idx >> 7, c8 = (idx & 127) * 8;
    bf16x8 vv = *(const bf16x8*)(adp + (size_t)(row0 + r) * Hdim + c8);
    *(bf16x8*)((char*)lA + r * 2048 + ((c8 * 2) ^ ((r & 7) << 4))) = vv;
  }

  float zacc[8];
  f32x4 acc[2][4];
#pragma unroll
  for (int j = 0; j < 8; ++j) zacc[j] = 0.f;
#pragma unroll
  for (int rf = 0; rf < 2; ++rf)
#pragma unroll
    for (int cf = 0; cf < 4; ++cf)
#pragma unroll
      for (int i = 0; i < 4; ++i) acc[rf][cf][i] = 0.f;

  __syncthreads();

  // ---------- t = 0: phase-1 only, then phase-2 ----------
  {
    int v0 = v0beg;
    f32x4 lacc[2][2];
#pragma unroll
    for (int rf = 0; rf < 2; ++rf)
#pragma unroll
      for (int cf = 0; cf < 2; ++cf)
#pragma unroll
        for (int i = 0; i < 4; ++i) lacc[rf][cf][i] = 0.f;
#pragma unroll 8
    for (int ks = 0; ks < 32; ++ks) {
      int kgl = ks * 32 + q * 8;
      bf16x8 af[2], bfr[2];
#pragma unroll
      for (int rf = 0; rf < 2; ++rf) {
        int r = rf * 16 + l15;
        af[rf] = *(const bf16x8*)((const char*)lA + r * 2048 + ((kgl * 2) ^ ((r & 7) << 4)));
      }
#pragma unroll
      for (int cf = 0; cf < 2; ++cf) {
        int vb = v0 / 16 + w * 2 + cf;
        bfr[cf] = *(const bf16x8*)(Bp1 + ((size_t)vb * 32 + ks) * 512 + lane * 8);
      }
#pragma unroll
      for (int rf = 0; rf < 2; ++rf)
#pragma unroll
        for (int cf = 0; cf < 2; ++cf)
          lacc[rf][cf] = mfma16(af[rf], bfr[cf], lacc[rf][cf]);
    }
    char* lPcur = (char*)lP[0];
#pragma unroll
    for (int rf = 0; rf < 2; ++rf)
#pragma unroll
      for (int i = 0; i < 4; ++i) {
        int r = rf * 16 + q * 4 + i;
#pragma unroll
        for (int cf = 0; cf < 2; ++cf) {
          int c0 = w * 32 + cf * 16;
          float pv = __expf(lacc[rf][cf][i]);
          zacc[rf * 4 + i] += pv;
          int c = c0 + l15;
          *(short*)(lPcur + r * 1024 + ((c * 2) ^ ((r & 7) << 4))) = f2bf(pv);
        }
      }
  }
  __syncthreads();

  // ---------- fused loop: phase-3(t-1) interleaved with phase-1(t) ----------
  for (int t = 1; t < nt; ++t) {
    int v0 = v0beg + t * VT;
    int v0p = v0 - VT;
    int rem = v0end - v0; if (rem > VT) rem = VT;   // 512, except 256 on sp1 tail
    char* lPprev = (char*)lP[(t - 1) & 1];
    char* lPcur  = (char*)lP[t & 1];
    f32x4 lacc[2][2];
#pragma unroll
    for (int rf = 0; rf < 2; ++rf)
#pragma unroll
      for (int cf = 0; cf < 2; ++cf)
#pragma unroll
        for (int i = 0; i < 4; ++i) lacc[rf][cf][i] = 0.f;
#pragma unroll 4
    for (int ks2 = 0; ks2 < 16; ++ks2) {
      // --- two phase-1 K-steps (tile t) ---
#pragma unroll
      for (int s = 0; s < 2; ++s) {
        int ks = ks2 * 2 + s;
        int kgl = ks * 32 + q * 8;
        bf16x8 af[2], bfr[2];
#pragma unroll
        for (int rf = 0; rf < 2; ++rf) {
          int r = rf * 16 + l15;
          af[rf] = *(const bf16x8*)((const char*)lA + r * 2048 + ((kgl * 2) ^ ((r & 7) << 4)));
        }
#pragma unroll
        for (int cf = 0; cf < 2; ++cf) {
          int vb = v0 / 16 + w * 2 + cf;
          if (vb > 1999) vb = 1999;     // clamp (sp1 tail; results gated by rem)
          bfr[cf] = *(const bf16x8*)(Bp1 + ((size_t)vb * 32 + ks) * 512 + lane * 8);
        }
#pragma unroll
        for (int rf = 0; rf < 2; ++rf)
#pragma unroll
          for (int cf = 0; cf < 2; ++cf)
            lacc[rf][cf] = mfma16(af[rf], bfr[cf], lacc[rf][cf]);
      }
      // --- one phase-3 K-step (tile t-1) ---
      {
        int kb = ks2 * 32 + q * 8;
        int vkb = v0p / 32 + ks2;
        if (vkb > 999) vkb = 999;       // clamp (tail; P=0 there)
        bf16x8 pa[2], bg[4];
#pragma unroll
        for (int rf = 0; rf < 2; ++rf) {
          int r = rf * 16 + l15;
          pa[rf] = *(const bf16x8*)(lPprev + r * 1024 + ((kb * 2) ^ ((r & 7) << 4)));
        }
#pragma unroll
        for (int cf = 0; cf < 4; ++cf)
          bg[cf] = *(const bf16x8*)(Bp2 + ((size_t)(w * 4 + cf) * 1000 + vkb) * 512 + lane * 8);
#pragma unroll
        for (int rf = 0; rf < 2; ++rf)
#pragma unroll
          for (int cf = 0; cf < 4; ++cf)
            acc[rf][cf] = mfma16(pa[rf], bg[cf], acc[rf][cf]);
      }
    }
    // --- phase 2 for tile t: P = exp(l) -> lP[t&1]; per-thread zacc only ---
#pragma unroll
    for (int rf = 0; rf < 2; ++rf)
#pragma unroll
      for (int i = 0; i < 4; ++i) {
        int r = rf * 16 + q * 4 + i;
#pragma unroll
        for (int cf = 0; cf < 2; ++cf) {
          int c0 = w * 32 + cf * 16;
          float pv = (c0 < rem) ? __expf(lacc[rf][cf][i]) : 0.f;
          zacc[rf * 4 + i] += pv;
          int c = c0 + l15;
          *(short*)(lPcur + r * 1024 + ((c * 2) ^ ((r & 7) << 4))) = f2bf(pv);
        }
      }
    __syncthreads();                    // ONLY barrier per tile
  }

  // ---------- final phase-3 for tile nt-1 ----------
  {
    int v0p = v0beg + (nt - 1) * VT;
    char* lPprev = (char*)lP[(nt - 1) & 1];
#pragma unroll 4
    for (int ks = 0; ks < 16; ++ks) {
      int kb = ks * 32 + q * 8;
      int vkb = v0p / 32 + ks;
      if (vkb > 999) vkb = 999;
      bf16x8 pa[2], bg[4];
#pragma unroll
      for (int rf = 0; rf < 2; ++rf) {
        int r = rf * 16 + l15;
        pa[rf] = *(const bf16x8*)(lPprev + r * 1024 + ((kb * 2) ^ ((r & 7) << 4)));
      }
#pragma unroll
      for (int cf = 0; cf < 4; ++cf)
        bg[cf] = *(const bf16x8*)(Bp2 + ((size_t)(w * 4 + cf) * 1000 + vkb) * 512 + lane * 8);
#pragma unroll
      for (int rf = 0; rf < 2; ++rf)
#pragma unroll
        for (int cf = 0; cf < 4; ++cf)
          acc[rf][cf] = mfma16(pa[rf], bg[cf], acc[rf][cf]);
    }
  }

  // ---------- epilogue: one z-reduce + dA-partial stores ----------
#pragma unroll
  for (int rf = 0; rf < 2; ++rf)
#pragma unroll
    for (int i = 0; i < 4; ++i) {
      float z = zacc[rf * 4 + i];
#pragma unroll
      for (int off = 1; off < 16; off <<= 1) z += __shfl_xor(z, off);
      if (l15 == 0) zred[(rf * 16 + q * 4 + i) * 16 + w] = z;
    }
  __syncthreads();
  if (tid < RB) {
    float z = 0.f;
#pragma unroll
    for (int g = 0; g < 16; ++g) z += zred[tid * 16 + g];
    zpart[sp * ROWS + row0 + tid] = z;
  }
#pragma unroll
  for (int rf = 0; rf < 2; ++rf)
#pragma unroll
    for (int cf = 0; cf < 4; ++cf)
#pragma unroll
      for (int i = 0; i < 4; ++i) {
        int r = rf * 16 + q * 4 + i;
        int h = w * 64 + cf * 16 + l15;
        dApart[((size_t)(row0 + r) * 2 + sp) * Hdim + h] = f2bf(acc[rf][cf][i]);
      }
}

// ===================== merge partials (in place per row) + loss =====================
__global__ void k_post(const short* __restrict__ adp, const float* __restrict__ lmhf,
                       const int* __restrict__ ids, const float* __restrict__ zpart,
                       char* __restrict__ dAx, float* __restrict__ loss_acc) {
  __shared__ float red[256];
  int row = blockIdx.x, tid = threadIdx.x;
  int b = row >> 11, s = row & 2047;
  bool valid = s < 2047;
  float Z = zpart[row] + zpart[ROWS + row];
  float sc = 1.f / (Z * NVALID);
  int tgt = valid ? ids[b * 2048 + s + 1] : 0;
  const short* prow = (const short*)(dAx + (size_t)row * 4096);
  float psum[4], lc[4], av[4];
#pragma unroll
  for (int i = 0; i < 4; ++i) {
    int h = i * 256 + tid;
    psum[i] = bf2f(prow[h]) + bf2f(prow[1024 + h]);
    lc[i] = lmhf[(size_t)h * Vdim + tgt];
    av[i] = bf2f(adp[(size_t)row * Hdim + h]);
  }
  __syncthreads();                          // all reads done before aliased writes
  float* drow = (float*)(dAx + (size_t)row * 4096);
  float dot = 0.f;
#pragma unroll
  for (int i = 0; i < 4; ++i) {
    int h = i * 256 + tid;
    drow[h] = valid ? (psum[i] * sc - lc[i] * (1.f / NVALID)) : 0.f;
    dot += av[i] * lc[i];
  }
  if (!valid) return;                       // block-uniform
  red[tid] = dot; __syncthreads();
  for (int o = 128; o; o >>= 1) {
    if (tid < o) red[tid] += red[tid + o];
    __syncthreads();
  }
  if (tid == 0) atomicAdd(loss_acc, (logf(Z) - red[0]) / NVALID);
}

// du = dA @ b^T : one wave per row (dA row stride 1024 floats)
__global__ void k_du(const float* __restrict__ dA, const float* __restrict__ fb,
                     float* __restrict__ du) {
  int w = threadIdx.x >> 6, lane = threadIdx.x & 63;
  int row = blockIdx.x * 4 + w;
  float acc[16];
#pragma unroll
  for (int r = 0; r < 16; ++r) acc[r] = 0.f;
  const float* dr = dA + (size_t)row * Hdim;
  for (int h = lane; h < Hdim; h += 64) {
    float dv = dr[h];
#pragma unroll
    for (int r = 0; r < 16; ++r) acc[r] += dv * fb[r * Hdim + h];
  }
#pragma unroll
  for (int r = 0; r < 16; ++r)
    for (int off = 32; off; off >>= 1) acc[r] += __shfl_xor(acc[r], off);
  if (lane == 0) {
#pragma unroll
    for (int r = 0; r < 16; ++r) du[row * Rdim + r] = acc[r];
  }
}

// ga = hs^T @ du ; gb = u^T @ dA  (atomic partials over row chunks)
__global__ void k_ga_gb(const float* __restrict__ hs, const float* __restrict__ dA,
                        const float* __restrict__ u, const float* __restrict__ du,
                        float* __restrict__ ga, float* __restrict__ gb) {
  __shared__ float lu[512 * 16], ldu[512 * 16];
  int tid = threadIdx.x;
  int h = blockIdx.x * 256 + tid;
  int r0 = blockIdx.y * 512;
#pragma unroll
  for (int i = 0; i < 32; ++i) {
    int idx = tid + i * 256;
    lu[idx] = u[(size_t)r0 * Rdim + idx];
    ldu[idx] = du[(size_t)r0 * Rdim + idx];
  }
  __syncthreads();
  float aga[16], agb[16];
#pragma unroll
  for (int r = 0; r < 16; ++r) { aga[r] = 0.f; agb[r] = 0.f; }
  for (int rl = 0; rl < 512; ++rl) {
    int row = r0 + rl;
    float hv = hs[(size_t)row * Hdim + h];
    float dv = dA[(size_t)row * Hdim + h];
#pragma unroll
    for (int r = 0; r < 16; ++r) {
      aga[r] += hv * ldu[rl * 16 + r];
      agb[r] += lu[rl * 16 + r] * dv;
    }
  }
#pragma unroll
  for (int r = 0; r < 16; ++r) {
    atomicAdd(&ga[h * Rdim + r], aga[r]);
    atomicAdd(&gb[r * Hdim + h], agb[r]);
  }
}

// grad_norm + parameter update + scalars
__global__ void k_finalize(const float* __restrict__ fa, const float* __restrict__ fb,
                           const float* __restrict__ ga, const float* __restrict__ gb,
                           const float* __restrict__ loss_acc, float* __restrict__ out) {
  __shared__ float red[512];
  int tid = threadIdx.x;
  float s = 0.f;
  for (int i = tid; i < 32768; i += 512) {
    float g = ga[i];           // ga||gb contiguous in workspace
    s += g * g;
  }
  red[tid] = s; __syncthreads();
  for (int o = 256; o; o >>= 1) {
    if (tid < o) red[tid] += red[tid + o];
    __syncthreads();
  }
  float gn = sqrtf(red[0]);
  for (int i = tid; i < 16384; i += 512) {
    out[OUT_A + i] = fa[i] - LRATE * ga[i];
    out[OUT_B + i] = fb[i] - LRATE * gb[i];
  }
  if (tid == 0) { out[OUT_LOSS] = loss_acc[0]; out[OUT_GN] = gn; }
}

// u2 = hs @ new_a (new_a read from d_out)
__global__ void k_u2(const float* __restrict__ hs, const float* __restrict__ na,
                     float* __restrict__ u2) {
  int w = threadIdx.x >> 6, lane = threadIdx.x & 63;
  int row = blockIdx.x * 4 + w;
  float acc[16];
#pragma unroll
  for (int r = 0; r < 16; ++r) acc[r] = 0.f;
  const float* hrow = hs + (size_t)row * Hdim;
  for (int h = lane; h < Hdim; h += 64) {
    float hv = hrow[h];
    const float* ar = na + h * Rdim;
#pragma unroll
    for (int r = 0; r < 16; ++r) acc[r] += hv * ar[r];
  }
#pragma unroll
  for (int r = 0; r < 16; ++r)
    for (int off = 32; off; off >>= 1) acc[r] += __shfl_xor(acc[r], off);
  if (lane == 0) {
#pragma unroll
    for (int r = 0; r < 16; ++r) u2[row * Rdim + r] = acc[r];
  }
}

// out = hs + u2 @ new_b (new_b read from d_out)
__global__ void k_out(const float* __restrict__ hs, const float* __restrict__ u2,
                      const float* __restrict__ nb, float* __restrict__ out) {
  size_t gid = (size_t)blockIdx.x * 256 + threadIdx.x;
  int row = (int)(gid >> 10), h = (int)(gid & 1023);
  const float* ur = u2 + row * Rdim;
  float v = hs[gid];
#pragma unroll
  for (int r = 0; r < 16; ++r) v += ur[r] * nb[r * Hdim + h];
  out[gid] = v;
}

extern "C" void kernel_launch(void* const* d_in, const int* in_sizes, int n_in,
                              void* d_out, int out_size, void* d_ws, size_t ws_size,
                              hipStream_t stream) {
  (void)in_sizes; (void)n_in; (void)out_size; (void)ws_size;
  const float* hs   = (const float*)d_in[0];
  const int*   ids  = (const int*)d_in[1];
  const float* fa   = (const float*)d_in[2];
  const float* fb   = (const float*)d_in[3];
  const float* lmhf = (const float*)d_in[4];
  float* out = (float*)d_out;
  char* ws = (char*)d_ws;

  short* Bp2    = (short*)(ws + OFF_BP2);
  short* Bp1    = (short*)(ws + OFF_BP1);
  short* adp    = (short*)(ws + OFF_ADP);
  char*  dAx    = ws + OFF_DA;
  float* u      = (float*)(ws + OFF_U);
  float* du     = (float*)(ws + OFF_DU);
  float* u2     = (float*)(ws + OFF_U2);
  float* zpart  = (float*)(ws + OFF_Z);
  float* ga     = (float*)(ws + OFF_GA);
  float* gb     = (float*)(ws + OFF_GB);
  float* loss_acc = (float*)(ws + OFF_LOSS);

  hipMemsetAsync(ws + OFF_GA, 0, 65536 * 2 + 4, stream);   // ga, gb, loss

  k_pack<<<dim3(125, 32), 256, 0, stream>>>(lmhf, Bp1, Bp2);
  k_u<<<1024, 256, 0, stream>>>(hs, fa, u);
  k_adapted<<<16384, 256, 0, stream>>>(hs, u, fb, adp);
  k_fused<<<256, 1024, 0, stream>>>(adp, Bp1, Bp2, (short*)dAx, zpart);
  k_post<<<4096, 256, 0, stream>>>(adp, lmhf, ids, zpart, dAx, loss_acc);
  k_du<<<1024, 256, 0, stream>>>((float*)dAx, fb, du);
  k_ga_gb<<<dim3(4, 8), 256, 0, stream>>>(hs, (float*)dAx, u, du, ga, gb);
  k_finalize<<<1, 512, 0, stream>>>(fa, fb, ga, gb, loss_acc, out);
  k_u2<<<1024, 256, 0, stream>>>(hs, out + OUT_A, u2);
  k_out<<<16384, 256, 0, stream>>>(hs, u2, out + OUT_B, out);
}

// Round 11
// 1085.030 us; speedup vs baseline: 1.3468x; 1.3468x over previous
//
#include <hip/hip_runtime.h>
#include <hip/hip_bf16.h>

// ---------------------------------------------------------------------------
// TTT meta-adapter fused step, round 11.
// rows = B*S = 4096, H = 1024, R = 16, V = 32000, N_valid = 4094.
// k_fused: R9 verbatim (best measured: RB=32, packed-B, lA staged once,
// lP double-buffered, one barrier/tile, m=0 softmax).
// Tail restructured: k_prep_ua (u+adapted fused), k_post_du (merge + target
// term via packed-Bp1 bf16 gather [268MB->33MB] + du fused), k_tail_uo
// (u2+out fused). 10 kernels -> 7.
// ---------------------------------------------------------------------------

#define ROWS 4096
#define Hdim 1024
#define Rdim 16
#define Vdim 32000
#define NVALID 4094.0f
#define LRATE 0.01f
#define RB 32          // rows per block in fused kernel
#define VT 512         // V-tile

typedef __attribute__((ext_vector_type(8))) short bf16x8;
typedef __attribute__((ext_vector_type(4))) float f32x4;

static __device__ __forceinline__ float bf2f(short u) {
  union { float f; unsigned int i; } w; w.i = ((unsigned int)(unsigned short)u) << 16; return w.f;
}
static __device__ __forceinline__ short f2bf(float f) {
  union { float f; unsigned int i; } w; w.f = f;
  unsigned int lsb = (w.i >> 16) & 1u;
  w.i += 0x7fffu + lsb;                 // round-to-nearest-even
  return (short)(w.i >> 16);
}
static __device__ __forceinline__ f32x4 mfma16(bf16x8 a, bf16x8 b, f32x4 c) {
  return __builtin_amdgcn_mfma_f32_16x16x32_bf16(a, b, c, 0, 0, 0);
}

// ---------------- workspace layout (bytes) ----------------
#define OFF_BP2   ((size_t)0)                    // lm_head packed [64][1000][512] bf16  65,536,000
#define OFF_BP1   ((size_t)65536000)             // lmhT packed [2000][32][512] bf16     65,536,000
#define OFF_ADP   ((size_t)131072000)            // adapted bf16 [ROWS][H]       8,388,608
#define OFF_DA    ((size_t)139460608)            // bf16 [ROWS][2][H]; f32 [ROWS][H] overlay  16,777,216
#define OFF_U     ((size_t)156237824)            // u f32                          262,144
#define OFF_DU    ((size_t)156499968)            // du f32                         262,144
#define OFF_Z     ((size_t)157024256)            // zpart f32 [2][ROWS]             32,768
#define OFF_GA    ((size_t)157089792)            // ga f32                          65,536
#define OFF_GB    ((size_t)157155328)            // gb f32                          65,536
#define OFF_LOSS  ((size_t)157220864)            // loss accumulator                     4

// ---------------- output layout (floats) ----------------
#define OUT_A    ((size_t)4194304)
#define OUT_B    ((size_t)4210688)
#define OUT_LOSS ((size_t)4227072)
#define OUT_GN   ((size_t)4227073)

// ===================== pack lm_head into fragment order =====================
// Bp1[vb][kb][lane][8]: element (v,k)=lm_head[k][v], lane=(v&15)+16*((k>>3)&3), j=k&7
// Bp2[hb][vkb][lane][8]: element (h,v)=lm_head[h][v], lane=(h&15)+16*((v>>3)&3), j=v&7
__global__ void k_pack(const float* __restrict__ in, short* __restrict__ Bp1,
                       short* __restrict__ Bp2) {
  __shared__ short tile[32][258];
  int v0 = blockIdx.x * 256, k0 = blockIdx.y * 32;
  int tid = threadIdx.x;
#pragma unroll
  for (int r = 0; r < 32; ++r)
    tile[r][tid] = f2bf(in[(size_t)(k0 + r) * Vdim + v0 + tid]);
  __syncthreads();
  int lane = tid & 63, l15 = lane & 15, q = (lane >> 4) & 3, g = tid >> 6;
#pragma unroll
  for (int it = 0; it < 4; ++it) {
    int vbl = it * 4 + g;                 // 0..15
    bf16x8 frag;
#pragma unroll
    for (int j = 0; j < 8; ++j) frag[j] = tile[q * 8 + j][vbl * 16 + l15];
    *(bf16x8*)(Bp1 + ((size_t)(v0 / 16 + vbl) * 32 + k0 / 32) * 512 + lane * 8) = frag;
  }
#pragma unroll
  for (int it = 0; it < 4; ++it) {
    int idx = it * 4 + g;                 // 0..15: hbl=idx>>3 (0..1), vkbl=idx&7
    int hbl = idx >> 3, vkbl = idx & 7;
    bf16x8 frag;
#pragma unroll
    for (int j = 0; j < 8; ++j) frag[j] = tile[hbl * 16 + l15][vkbl * 32 + q * 8 + j];
    *(bf16x8*)(Bp2 + ((size_t)(k0 / 16 + hbl) * 1000 + v0 / 32 + vkbl) * 512 + lane * 8) = frag;
  }
}

// ===================== fused u + adapted: one block per row =====================
__global__ void k_prep_ua(const float* __restrict__ hs, const float* __restrict__ fa,
                          const float* __restrict__ fb, float* __restrict__ u,
                          short* __restrict__ adp) {
  __shared__ float wred[4][16];
  __shared__ float ubc[16];
  int row = blockIdx.x, tid = threadIdx.x, lane = tid & 63, w = tid >> 6;
  const float* hrow = hs + (size_t)row * Hdim;
  float4 hv = *(const float4*)(hrow + tid * 4);
  float ur[16];
  const float* fap = fa + (size_t)tid * 4 * Rdim;
#pragma unroll
  for (int r = 0; r < 16; ++r)
    ur[r] = hv.x * fap[r] + hv.y * fap[16 + r] + hv.z * fap[32 + r] + hv.w * fap[48 + r];
#pragma unroll
  for (int r = 0; r < 16; ++r)
#pragma unroll
    for (int off = 32; off; off >>= 1) ur[r] += __shfl_xor(ur[r], off);
  if (lane == 0) {
#pragma unroll
    for (int r = 0; r < 16; ++r) wred[w][r] = ur[r];
  }
  __syncthreads();
  if (tid < 16) {
    float s = wred[0][tid] + wred[1][tid] + wred[2][tid] + wred[3][tid];
    ubc[tid] = s;
    u[row * Rdim + tid] = s;
  }
  __syncthreads();
  float a0 = hv.x, a1 = hv.y, a2 = hv.z, a3 = hv.w;
#pragma unroll
  for (int r = 0; r < 16; ++r) {
    float uv = ubc[r];
    float4 bv = *(const float4*)(fb + r * Hdim + tid * 4);
    a0 += uv * bv.x; a1 += uv * bv.y; a2 += uv * bv.z; a3 += uv * bv.w;
  }
  short4 o; o.x = f2bf(a0); o.y = f2bf(a1); o.z = f2bf(a2); o.w = f2bf(a3);
  *(short4*)(adp + (size_t)row * Hdim + tid * 4) = o;
}

// ===================== fused logits + exp + dA partials (R9 verbatim) ==============
// grid 256 (XCD-swizzled -> 128 rowgroups x 2 V-splits), 1024 threads (16 waves).
__launch_bounds__(1024, 4)
__global__ void k_fused(const short* __restrict__ adp, const short* __restrict__ Bp1,
                        const short* __restrict__ Bp2, short* __restrict__ dApart,
                        float* __restrict__ zpart) {
  __shared__ __align__(16) short lA[RB * 1024];   // adapted rows, full K (swizzled)  64 KB
  __shared__ __align__(16) short lP[2][RB * VT];  // P tile bf16, double-buffered   2x32 KB
  __shared__ float zred[RB * 16];                 //                                   2 KB
  int tid = threadIdx.x, lane = tid & 63, w = tid >> 6;      // w in [0,16)
  int q = lane >> 4, l15 = lane & 15;
  // XCD swizzle: XCDs 0-3 get split 0, XCDs 4-7 get split 1
  int L = blockIdx.x;
  int sp = (L >> 2) & 1;
  int rg = (L & 3) | ((L >> 3) << 2);
  int row0 = rg * RB;
  int v0beg = sp ? 15872 : 0;
  int v0end = sp ? 32000 : 15872;
  int nt = sp ? 32 : 31;

  // stage adapted rows once (read-only afterwards)
#pragma unroll
  for (int i = 0; i < 4; ++i) {
    int idx = tid + i * 1024;
    int r = idx >> 7, c8 = (idx & 127) * 8;
    bf16x8 vv = *(const bf16x8*)(adp + (size_t)(row0 + r) * Hdim + c8);
    *(bf16x8*)((char*)lA + r * 2048 + ((c8 * 2) ^ ((r & 7) << 4))) = vv;
  }
  if (tid < RB * 16) zred[tid] = 0.f;

  float zacc[8];
  f32x4 acc[2][4];
#pragma unroll
  for (int j = 0; j < 8; ++j) zacc[j] = 0.f;
#pragma unroll
  for (int rf = 0; rf < 2; ++rf)
#pragma unroll
    for (int cf = 0; cf < 4; ++cf)
#pragma unroll
      for (int i = 0; i < 4; ++i) acc[rf][cf][i] = 0.f;

  __syncthreads();

  for (int t = 0; t < nt; ++t) {
    int v0 = v0beg + t * VT;
    int rem = v0end - v0; if (rem > VT) rem = VT;   // 512, except 256 on sp1 tail
    char* lPc = (char*)lP[t & 1];
    // ---------- phase 1: logits; wave w owns cols w*32..+32 ----------
    f32x4 lacc[2][2];
#pragma unroll
    for (int rf = 0; rf < 2; ++rf)
#pragma unroll
      for (int cf = 0; cf < 2; ++cf)
#pragma unroll
        for (int i = 0; i < 4; ++i) lacc[rf][cf][i] = 0.f;
#pragma unroll 8
    for (int ks = 0; ks < 32; ++ks) {
      int kgl = ks * 32 + q * 8;
      bf16x8 af[2], bfr[2];
#pragma unroll
      for (int rf = 0; rf < 2; ++rf) {
        int r = rf * 16 + l15;
        af[rf] = *(const bf16x8*)((const char*)lA + r * 2048 + ((kgl * 2) ^ ((r & 7) << 4)));
      }
#pragma unroll
      for (int cf = 0; cf < 2; ++cf) {
        int vb = v0 / 16 + w * 2 + cf;
        if (vb > 1999) vb = 1999;       // clamp (sp1 tail; results gated by rem)
        bfr[cf] = *(const bf16x8*)(Bp1 + ((size_t)vb * 32 + ks) * 512 + lane * 8);
      }
#pragma unroll
      for (int rf = 0; rf < 2; ++rf)
#pragma unroll
        for (int cf = 0; cf < 2; ++cf)
          lacc[rf][cf] = mfma16(af[rf], bfr[cf], lacc[rf][cf]);
    }
    // ---------- phase 2: P = exp(l) (m=0) -> lP[t&1]; Z into zred ----------
#pragma unroll
    for (int rf = 0; rf < 2; ++rf)
#pragma unroll
      for (int i = 0; i < 4; ++i) {
        int r = rf * 16 + q * 4 + i;
        float z = 0.f;
#pragma unroll
        for (int cf = 0; cf < 2; ++cf) {
          int c0 = w * 32 + cf * 16;
          float pv = (c0 < rem) ? __expf(lacc[rf][cf][i]) : 0.f;
          z += pv;
          int c = c0 + l15;
          *(short*)(lPc + r * 1024 + ((c * 2) ^ ((r & 7) << 4))) = f2bf(pv);
        }
#pragma unroll
        for (int off = 1; off < 16; off <<= 1) z += __shfl_xor(z, off);
        if (l15 == 0) zred[r * 16 + w] += z;
      }
    __syncthreads();                    // ONLY barrier: lP[t&1] RAW
    // ---------- phase 3: acc += P @ lm_head^T; wave w owns h w*64..+64 ----------
#pragma unroll 4
    for (int ks = 0; ks < 16; ++ks) {
      int kb = ks * 32 + q * 8;
      int vkb = v0 / 32 + ks;
      if (vkb > 999) vkb = 999;         // clamp (tail; P=0 there)
      bf16x8 pa[2], bg[4];
#pragma unroll
      for (int rf = 0; rf < 2; ++rf) {
        int r = rf * 16 + l15;
        pa[rf] = *(const bf16x8*)(lPc + r * 1024 + ((kb * 2) ^ ((r & 7) << 4)));
      }
#pragma unroll
      for (int cf = 0; cf < 4; ++cf)
        bg[cf] = *(const bf16x8*)(Bp2 + ((size_t)(w * 4 + cf) * 1000 + vkb) * 512 + lane * 8);
#pragma unroll
      for (int rf = 0; rf < 2; ++rf)
#pragma unroll
        for (int cf = 0; cf < 4; ++cf)
          acc[rf][cf] = mfma16(pa[rf], bg[cf], acc[rf][cf]);
    }
    // no trailing barrier: next tile writes the OTHER lP buffer (max drift 1 tile)
  }
  // ---------- epilogue: Z totals + dA-partial stores ----------
  __syncthreads();
  if (tid < RB) {
    float z = 0.f;
#pragma unroll
    for (int g = 0; g < 16; ++g) z += zred[tid * 16 + g];
    zpart[sp * ROWS + row0 + tid] = z;
  }
#pragma unroll
  for (int rf = 0; rf < 2; ++rf)
#pragma unroll
    for (int cf = 0; cf < 4; ++cf)
#pragma unroll
      for (int i = 0; i < 4; ++i) {
        int r = rf * 16 + q * 4 + i;
        int h = w * 64 + cf * 16 + l15;
        dApart[((size_t)(row0 + r) * 2 + sp) * Hdim + h] = f2bf(acc[rf][cf][i]);
      }
}

// ===================== merge partials + target term (Bp1 gather) + du + loss =======
__global__ void k_post_du(const short* __restrict__ adp, const short* __restrict__ Bp1,
                          const float* __restrict__ fb, const int* __restrict__ ids,
                          const float* __restrict__ zpart, char* __restrict__ dAx,
                          float* __restrict__ du, float* __restrict__ loss_acc) {
  __shared__ float red[256];
  __shared__ float wredu[4][16];
  int row = blockIdx.x, tid = threadIdx.x, lane = tid & 63, w = tid >> 6;
  int b = row >> 11, s = row & 2047;
  bool valid = s < 2047;
  float Z = zpart[row] + zpart[ROWS + row];
  float sc = 1.f / (Z * NVALID);
  int tgt = valid ? ids[b * 2048 + s + 1] : 0;
  const short* prow = (const short*)(dAx + (size_t)row * 4096);
  size_t vbb = (size_t)(tgt >> 4) * 32;
  int l15t = tgt & 15;
  short4 p0 = *(const short4*)(prow + tid * 4);
  short4 p1 = *(const short4*)(prow + 1024 + tid * 4);
  short4 a4 = *(const short4*)(adp + (size_t)row * Hdim + tid * 4);
  float lcv[4], d[4];
#pragma unroll
  for (int c = 0; c < 4; ++c) {
    int h = tid * 4 + c;
    // lm_head[h][tgt] from packed Bp1: 16B-granular gather (vs 64B-line fp32 gather)
    short lcs = Bp1[(vbb + (h >> 5)) * 512 + (size_t)((l15t + 16 * ((h >> 3) & 3)) * 8 + (h & 7))];
    lcv[c] = bf2f(lcs);
  }
  float pp0[4] = {bf2f(p0.x), bf2f(p0.y), bf2f(p0.z), bf2f(p0.w)};
  float pp1[4] = {bf2f(p1.x), bf2f(p1.y), bf2f(p1.z), bf2f(p1.w)};
  float avv[4] = {bf2f(a4.x), bf2f(a4.y), bf2f(a4.z), bf2f(a4.w)};
#pragma unroll
  for (int c = 0; c < 4; ++c)
    d[c] = valid ? ((pp0[c] + pp1[c]) * sc - lcv[c] * (1.f / NVALID)) : 0.f;
  __syncthreads();                          // all bf16 partial reads before f32 overwrite
  float* drow = (float*)(dAx + (size_t)row * 4096);
  float dot = 0.f;
#pragma unroll
  for (int c = 0; c < 4; ++c) {
    drow[tid * 4 + c] = d[c];
    dot += avv[c] * lcv[c];
  }
  // du[r] = sum_h dA[h] * fb[r][h]
  float pdu[16];
#pragma unroll
  for (int r = 0; r < 16; ++r) {
    float4 bv = *(const float4*)(fb + r * Hdim + tid * 4);
    pdu[r] = d[0] * bv.x + d[1] * bv.y + d[2] * bv.z + d[3] * bv.w;
  }
#pragma unroll
  for (int r = 0; r < 16; ++r)
#pragma unroll
    for (int off = 32; off; off >>= 1) pdu[r] += __shfl_xor(pdu[r], off);
  if (lane == 0) {
#pragma unroll
    for (int r = 0; r < 16; ++r) wredu[w][r] = pdu[r];
  }
  red[tid] = dot;
  __syncthreads();
  if (tid < 16)
    du[row * Rdim + tid] = wredu[0][tid] + wredu[1][tid] + wredu[2][tid] + wredu[3][tid];
  if (!valid) return;                       // block-uniform
  for (int o = 128; o; o >>= 1) {
    if (tid < o) red[tid] += red[tid + o];
    __syncthreads();
  }
  if (tid == 0) atomicAdd(loss_acc, (logf(Z) - red[0]) / NVALID);
}

// ga = hs^T @ du ; gb = u^T @ dA  (atomic partials over row chunks)
__global__ void k_ga_gb(const float* __restrict__ hs, const float* __restrict__ dA,
                        const float* __restrict__ u, const float* __restrict__ du,
                        float* __restrict__ ga, float* __restrict__ gb) {
  __shared__ float lu[512 * 16], ldu[512 * 16];
  int tid = threadIdx.x;
  int h = blockIdx.x * 256 + tid;
  int r0 = blockIdx.y * 512;
#pragma unroll
  for (int i = 0; i < 32; ++i) {
    int idx = tid + i * 256;
    lu[idx] = u[(size_t)r0 * Rdim + idx];
    ldu[idx] = du[(size_t)r0 * Rdim + idx];
  }
  __syncthreads();
  float aga[16], agb[16];
#pragma unroll
  for (int r = 0; r < 16; ++r) { aga[r] = 0.f; agb[r] = 0.f; }
  for (int rl = 0; rl < 512; ++rl) {
    int row = r0 + rl;
    float hv = hs[(size_t)row * Hdim + h];
    float dv = dA[(size_t)row * Hdim + h];
#pragma unroll
    for (int r = 0; r < 16; ++r) {
      aga[r] += hv * ldu[rl * 16 + r];
      agb[r] += lu[rl * 16 + r] * dv;
    }
  }
#pragma unroll
  for (int r = 0; r < 16; ++r) {
    atomicAdd(&ga[h * Rdim + r], aga[r]);
    atomicAdd(&gb[r * Hdim + h], agb[r]);
  }
}

// grad_norm + parameter update + scalars
__global__ void k_finalize(const float* __restrict__ fa, const float* __restrict__ fb,
                           const float* __restrict__ ga, const float* __restrict__ gb,
                           const float* __restrict__ loss_acc, float* __restrict__ out) {
  __shared__ float red[512];
  int tid = threadIdx.x;
  float s = 0.f;
  for (int i = tid; i < 32768; i += 512) {
    float g = ga[i];           // ga||gb contiguous in workspace
    s += g * g;
  }
  red[tid] = s; __syncthreads();
  for (int o = 256; o; o >>= 1) {
    if (tid < o) red[tid] += red[tid + o];
    __syncthreads();
  }
  float gn = sqrtf(red[0]);
  for (int i = tid; i < 16384; i += 512) {
    out[OUT_A + i] = fa[i] - LRATE * ga[i];
    out[OUT_B + i] = fb[i] - LRATE * gb[i];
  }
  if (tid == 0) { out[OUT_LOSS] = loss_acc[0]; out[OUT_GN] = gn; }
}

// ===================== fused u2 + out: one block per row =====================
__global__ void k_tail_uo(const float* __restrict__ hs, const float* __restrict__ outAB,
                          float* __restrict__ out) {
  __shared__ float wred[4][16];
  __shared__ float ubc[16];
  int row = blockIdx.x, tid = threadIdx.x, lane = tid & 63, w = tid >> 6;
  const float* na = outAB;              // new_a [H][R]
  const float* nb = outAB + 16384;      // new_b [R][H]
  const float* hrow = hs + (size_t)row * Hdim;
  float4 hv = *(const float4*)(hrow + tid * 4);
  float ur[16];
  const float* nap = na + (size_t)tid * 4 * Rdim;
#pragma unroll
  for (int r = 0; r < 16; ++r)
    ur[r] = hv.x * nap[r] + hv.y * nap[16 + r] + hv.z * nap[32 + r] + hv.w * nap[48 + r];
#pragma unroll
  for (int r = 0; r < 16; ++r)
#pragma unroll
    for (int off = 32; off; off >>= 1) ur[r] += __shfl_xor(ur[r], off);
  if (lane == 0) {
#pragma unroll
    for (int r = 0; r < 16; ++r) wred[w][r] = ur[r];
  }
  __syncthreads();
  if (tid < 16) ubc[tid] = wred[0][tid] + wred[1][tid] + wred[2][tid] + wred[3][tid];
  __syncthreads();
  float a0 = hv.x, a1 = hv.y, a2 = hv.z, a3 = hv.w;
#pragma unroll
  for (int r = 0; r < 16; ++r) {
    float uv = ubc[r];
    float4 bv = *(const float4*)(nb + r * Hdim + tid * 4);
    a0 += uv * bv.x; a1 += uv * bv.y; a2 += uv * bv.z; a3 += uv * bv.w;
  }
  float4 o; o.x = a0; o.y = a1; o.z = a2; o.w = a3;
  *(float4*)(out + (size_t)row * Hdim + tid * 4) = o;
}

extern "C" void kernel_launch(void* const* d_in, const int* in_sizes, int n_in,
                              void* d_out, int out_size, void* d_ws, size_t ws_size,
                              hipStream_t stream) {
  (void)in_sizes; (void)n_in; (void)out_size; (void)ws_size;
  const float* hs   = (const float*)d_in[0];
  const int*   ids  = (const int*)d_in[1];
  const float* fa   = (const float*)d_in[2];
  const float* fb   = (const float*)d_in[3];
  const float* lmhf = (const float*)d_in[4];
  float* out = (float*)d_out;
  char* ws = (char*)d_ws;

  short* Bp2    = (short*)(ws + OFF_BP2);
  short* Bp1    = (short*)(ws + OFF_BP1);
  short* adp    = (short*)(ws + OFF_ADP);
  char*  dAx    = ws + OFF_DA;
  float* u      = (float*)(ws + OFF_U);
  float* du     = (float*)(ws + OFF_DU);
  float* zpart  = (float*)(ws + OFF_Z);
  float* ga     = (float*)(ws + OFF_GA);
  float* gb     = (float*)(ws + OFF_GB);
  float* loss_acc = (float*)(ws + OFF_LOSS);

  hipMemsetAsync(ws + OFF_GA, 0, 65536 * 2 + 4, stream);   // ga, gb, loss

  k_pack<<<dim3(125, 32), 256, 0, stream>>>(lmhf, Bp1, Bp2);
  k_prep_ua<<<4096, 256, 0, stream>>>(hs, fa, fb, u, adp);
  k_fused<<<256, 1024, 0, stream>>>(adp, Bp1, Bp2, (short*)dAx, zpart);
  k_post_du<<<4096, 256, 0, stream>>>(adp, Bp1, fb, ids, zpart, dAx, du, loss_acc);
  k_ga_gb<<<dim3(4, 8), 256, 0, stream>>>(hs, (float*)dAx, u, du, ga, gb);
  k_finalize<<<1, 512, 0, stream>>>(fa, fb, ga, gb, loss_acc, out);
  k_tail_uo<<<4096, 256, 0, stream>>>(hs, out + OUT_A, out);
}